// Round 6
// baseline (6224.582 us; speedup 1.0000x reference)
//
#include <hip/hip_runtime.h>
#include <stdint.h>

#define H_DIM   1024
#define G3      3072
#define EMB     50
#define TSTEPS  100
#define NB      4096
#define NLABEL  15

typedef __bf16 bf16x8 __attribute__((ext_vector_type(8)));
typedef float  f32x4  __attribute__((ext_vector_type(4)));

__device__ inline uint16_t f2bf(float f) {
  uint32_t u = __builtin_bit_cast(uint32_t, f);
  u += 0x7FFFu + ((u >> 16) & 1u);   // round-to-nearest-even
  return (uint16_t)(u >> 16);
}

__device__ inline void gld16(const void* g, void* l) {
  __builtin_amdgcn_global_load_lds(
      (const __attribute__((address_space(1))) uint32_t*)g,
      (__attribute__((address_space(3))) uint32_t*)l, 16, 0, 0);
}

#define BARF() do { __builtin_amdgcn_s_barrier(); \
                    asm volatile("" ::: "memory"); } while (0)

// ---------------- prep kernels (buffers stay LINEAR) ----------------

__global__ __launch_bounds__(256) void prep_recT(const float* __restrict__ rec,
                                                 uint16_t* __restrict__ recT) {
  __shared__ uint16_t st[64][72];
  const int n0 = blockIdx.x * 64;
  const int k0 = blockIdx.y * 64;
  const int tid = threadIdx.x;
#pragma unroll
  for (int i = 0; i < 16; ++i) {
    int idx = tid + i * 256;
    int r = idx >> 6;
    int c = idx & 63;
    st[c][r] = f2bf(rec[(size_t)(k0 + r) * G3 + n0 + c]);
  }
  __syncthreads();
#pragma unroll
  for (int i = 0; i < 16; ++i) {
    int idx = tid + i * 256;
    int r = idx >> 6;
    int c = idx & 63;
    recT[(size_t)(n0 + r) * H_DIM + k0 + c] = st[r][c];
  }
}

__global__ __launch_bounds__(256) void prep_kerT(const float* __restrict__ ker,
                                                 uint16_t* __restrict__ kerT) {
  int n = blockIdx.x * 4 + (threadIdx.x >> 6);
  int k = threadIdx.x & 63;
  float v = (k < EMB) ? ker[(size_t)k * G3 + n] : 0.f;
  kerT[(size_t)n * 64 + k] = f2bf(v);
}

__global__ __launch_bounds__(256) void prep_embt(const int* __restrict__ x,
                                                 const float* __restrict__ tab,
                                                 uint16_t* __restrict__ embt) {
  int idx = blockIdx.x * 256 + threadIdx.x;
  int g = idx >> 5;
  int p = idx & 31;
  int t = g >> 12;
  int b = g & 4095;
  int row = x[b * TSTEPS + t];
  float2 v;
  if (p < 25) v = *reinterpret_cast<const float2*>(tab + (size_t)row * EMB + 2 * p);
  else { v.x = 0.f; v.y = 0.f; }
  uint32_t packed = (uint32_t)f2bf(v.x) | ((uint32_t)f2bf(v.y) << 16);
  *reinterpret_cast<uint32_t*>(embt + (size_t)g * 64 + 2 * p) = packed;
}

// ---------------- persistent GRU (all 100 steps in one kernel) ----------------
// grid 256 (1 block/CU, cooperative), block 512 (8 waves, 2x4). Per-step tile:
// 128 rows x 128 cols, 3 gates, r5's counted-vmcnt phased pipeline. Between
// steps: row-group sync (8 blocks sharing rowblk) via device-scope
// release-add / acquire-spin + threadfence. h carried in REGISTERS (hreg);
// hf written only at the final step.
__global__ __launch_bounds__(512, 2) void gru_persistent(
    uint16_t* __restrict__ hb0,             // [4096][1024] bf16 (t even read)
    uint16_t* __restrict__ hb1,             // [4096][1024] bf16
    float* __restrict__ hf,                 // [4096][1024] f32 (final only)
    const uint16_t* __restrict__ recT,      // [3072][1024] bf16
    const uint16_t* __restrict__ kerT,      // [3072][64]   bf16
    const uint16_t* __restrict__ embt_all,  // [100][4096][64] bf16
    const float* __restrict__ bias_i,       // [3072]
    const float* __restrict__ bias_r,       // [3072]
    uint32_t* __restrict__ cnt) {           // [32] rowgroup counters (zeroed)
  __shared__ __align__(16) uint16_t sA2[2][128 * 64];      // 32 KB
  __shared__ __align__(16) uint16_t sP[2][3][128 * 64];    // 96 KB

  const int tid  = threadIdx.x;
  const int lane = tid & 63;
  const int wid  = tid >> 6;
  const int wm   = wid >> 2;
  const int wn   = wid & 3;
  const int bid  = blockIdx.x;
  // XCD remap: each XCD = 8 row-blocks x 4 col-blocks
  const int xk = bid & 7, slot = bid >> 3;
  const int rowblk = (xk >> 1) * 8 + (slot >> 2);   // 0..31 (= rowgroup)
  const int colblk = (xk & 1) * 4 + (slot & 3);     // 0..7
  const int r0 = rowblk * 128;
  const int j0 = colblk * 128;

  const int swz8 = 8 * ((lane & 7) ^ (lane >> 3));

  // biases (step-invariant) hoisted
  float c_bz[2], c_br[2], c_bih[2], c_brh[2];
#pragma unroll
  for (int nf = 0; nf < 2; ++nf) {
    int col = j0 + wn * 32 + nf * 16 + (lane & 15);
    c_bz[nf]  = bias_i[col] + bias_r[col];
    c_br[nf]  = bias_i[H_DIM + col] + bias_r[H_DIM + col];
    c_bih[nf] = bias_i[2 * H_DIM + col];
    c_brh[nf] = bias_r[2 * H_DIM + col];
  }

  // h carried in registers, layout mirrors acc[mf][nf]
  f32x4 hreg[4][2];
#pragma unroll
  for (int m = 0; m < 4; ++m)
#pragma unroll
    for (int n = 0; n < 2; ++n) hreg[m][n] = (f32x4){0.f, 0.f, 0.f, 0.f};

  bf16x8 af[4][2];
  bf16x8 bf0[2][2], bf1[2][2];
  f32x4 accZ[4][2], accR[4][2], accH[4][2], accX[4][2];

  for (int s = 0; s < TSTEPS; ++s) {
    const uint16_t* __restrict__ hb_prev = (s & 1) ? hb1 : hb0;
    uint16_t* __restrict__ hb_next       = (s & 1) ? hb0 : hb1;
    const uint16_t* __restrict__ emb = embt_all + (size_t)s * NB * 64;

#pragma unroll
    for (int m = 0; m < 4; ++m)
#pragma unroll
      for (int n = 0; n < 2; ++n) {
        accZ[m][n] = (f32x4){0.f, 0.f, 0.f, 0.f};
        accR[m][n] = (f32x4){0.f, 0.f, 0.f, 0.f};
        accH[m][n] = (f32x4){0.f, 0.f, 0.f, 0.f};
        accX[m][n] = (f32x4){0.f, 0.f, 0.f, 0.f};
      }

    auto stageA = [&](int t) {
      const int abuf = t & 1;
#pragma unroll
      for (int i = 0; i < 2; ++i) {
        int row = wid * 16 + i * 8 + (lane >> 3);
        const uint16_t* src = (t < 16)
            ? hb_prev + (size_t)(r0 + row) * H_DIM + t * 64 + swz8
            : emb + (size_t)(r0 + row) * 64 + swz8;
        gld16(src, &sA2[abuf][(wid * 128 + i * 64 + lane) * 8]);
      }
    };
    auto stageP = [&](int t, int g) {
      const int pbuf = t & 1;
#pragma unroll
      for (int i = 0; i < 2; ++i) {
        int c = wid * 2 + i;
        int n = c * 8 + (lane >> 3);
        const uint16_t* src = (t < 16)
            ? recT + ((size_t)g * H_DIM + j0 + n) * H_DIM + t * 64 + swz8
            : kerT + ((size_t)g * H_DIM + j0 + n) * 64 + swz8;
        gld16(src, &sP[pbuf][g][(c * 64 + lane) * 8]);
      }
    };
    auto readA = [&](int t) {
      const int abuf = t & 1;
#pragma unroll
      for (int ks = 0; ks < 2; ++ks) {
        const int colswz = (ks * 32 + (lane >> 4) * 8) ^ ((lane & 7) << 3);
#pragma unroll
        for (int mf = 0; mf < 4; ++mf)
          af[mf][ks] = *reinterpret_cast<const bf16x8*>(
              &sA2[abuf][(wm * 64 + mf * 16 + (lane & 15)) * 64 + colswz]);
      }
    };
    auto readB = [&](int t, int g, bf16x8 (&bf)[2][2]) {
      const int pbuf = t & 1;
#pragma unroll
      for (int ks = 0; ks < 2; ++ks) {
        const int colswz = (ks * 32 + (lane >> 4) * 8) ^ ((lane & 7) << 3);
#pragma unroll
        for (int nf = 0; nf < 2; ++nf) {
          int nn = wn * 32 + nf * 16 + (lane & 15);
          bf[nf][ks] = *reinterpret_cast<const bf16x8*>(&sP[pbuf][g][nn * 64 + colswz]);
        }
      }
    };
    auto MF = [&](bf16x8 (&bf)[2][2], f32x4 (&acc)[4][2]) {
      __builtin_amdgcn_s_setprio(1);
#pragma unroll
      for (int ks = 0; ks < 2; ++ks)
#pragma unroll
        for (int nf = 0; nf < 2; ++nf)
#pragma unroll
          for (int mf = 0; mf < 4; ++mf)
            acc[mf][nf] = __builtin_amdgcn_mfma_f32_16x16x32_bf16(
                af[mf][ks], bf[nf][ks], acc[mf][nf], 0, 0, 0);
      __builtin_amdgcn_s_setprio(0);
    };

#define PH(DSRD, MFBUF, MFACC, STG, WN) do { \
    DSRD; MF(MFBUF, MFACC); STG; \
    asm volatile("s_waitcnt vmcnt(" #WN ")" ::: "memory"); \
    BARF(); \
  } while (0)
#define PHH(MFBUF, MFACC, DSRD, STG, WN) do { \
    MF(MFBUF, MFACC); DSRD; STG; \
    asm volatile("s_waitcnt vmcnt(" #WN ")" ::: "memory"); \
    BARF(); \
  } while (0)
#define TILE_STEADY(t, BFA, BFB) do { \
    PH(readB(t, 1, BFB), BFA, accZ, stageP((t) + 1, 1), 6); \
    PH(readB(t, 2, BFA), BFB, accR, stageP((t) + 1, 2), 4); \
    PHH(BFA, accH, (readA((t) + 1), readB((t) + 1, 0, BFB)), \
        (stageA((t) + 2), stageP((t) + 2, 0)), 6); \
  } while (0)

    // prologue
    stageA(0); stageP(0, 0); stageP(0, 1); stageP(0, 2);
    stageA(1); stageP(1, 0);
    asm volatile("s_waitcnt vmcnt(0)" ::: "memory");
    BARF();
    readA(0); readB(0, 0, bf0);

    for (int tt = 0; tt < 14; tt += 2) {
      TILE_STEADY(tt, bf0, bf1);
      TILE_STEADY(tt + 1, bf1, bf0);
    }
    TILE_STEADY(14, bf0, bf1);
    PH(readB(15, 1, bf0), bf1, accZ, stageP(16, 1), 6);
    PH(readB(15, 2, bf1), bf0, accR, stageP(16, 2), 4);
    PHH(bf1, accH, (readA(16), readB(16, 0, bf0)), (void)0, 2);
    PH(readB(16, 1, bf1), bf0, accZ, (void)0, 0);
    PH(readB(16, 2, bf0), bf1, accR, (void)0, 0);
    MF(bf0, accX);

#undef PH
#undef PHH
#undef TILE_STEADY

    // epilogue: gates in fp32; h kept in hreg; write bf16 h for next step
#pragma unroll
    for (int nf = 0; nf < 2; ++nf) {
      int col = j0 + wn * 32 + nf * 16 + (lane & 15);
#pragma unroll
      for (int mf = 0; mf < 4; ++mf) {
#pragma unroll
        for (int q = 0; q < 4; ++q) {
          int row = r0 + wm * 64 + mf * 16 + (lane >> 4) * 4 + q;
          float z  = 1.f / (1.f + __expf(-(accZ[mf][nf][q] + c_bz[nf])));
          float rr = 1.f / (1.f + __expf(-(accR[mf][nf][q] + c_br[nf])));
          float pre = accX[mf][nf][q] + c_bih[nf] +
                      rr * (accH[mf][nf][q] + c_brh[nf]);
          float hc  = 2.f / (1.f + __expf(-2.f * pre)) - 1.f;   // tanh
          float hnew = z * hreg[mf][nf][q] + (1.f - z) * hc;
          hreg[mf][nf][q] = hnew;
          size_t idx = (size_t)row * H_DIM + col;
          hb_next[idx] = f2bf(hnew);
          if (s == TSTEPS - 1) hf[idx] = hnew;
        }
      }
    }

    // row-group sync: 8 blocks sharing rowblk. release-add, acquire-spin.
    __syncthreads();                       // drains each wave's stores
    if (tid == 0) {
      __threadfence();                     // agent-scope release (L2 wb)
      __hip_atomic_fetch_add(&cnt[rowblk], 1u, __ATOMIC_RELEASE,
                             __HIP_MEMORY_SCOPE_AGENT);
      const uint32_t target = 8u * (uint32_t)(s + 1);
      while (__hip_atomic_load(&cnt[rowblk], __ATOMIC_ACQUIRE,
                               __HIP_MEMORY_SCOPE_AGENT) < target)
        __builtin_amdgcn_s_sleep(2);
    }
    __syncthreads();                       // all waves see acquired state
  }
}

// ---------------- final logits ----------------
__global__ __launch_bounds__(64) void logits_kernel(const float* __restrict__ hf,
                                                    const float* __restrict__ Wd,
                                                    const float* __restrict__ bd,
                                                    float* __restrict__ out) {
  int b = blockIdx.x;
  int l = threadIdx.x;
  float p[NLABEL];
#pragma unroll
  for (int o = 0; o < NLABEL; ++o) p[o] = 0.f;
  for (int kb = 0; kb < 16; ++kb) {
    int k = kb * 64 + l;
    float hv = hf[(size_t)b * H_DIM + k];
#pragma unroll
    for (int o = 0; o < NLABEL; ++o) p[o] += hv * Wd[k * NLABEL + o];
  }
#pragma unroll
  for (int o = 0; o < NLABEL; ++o) {
#pragma unroll
    for (int s = 32; s; s >>= 1) p[o] += __shfl_xor(p[o], s);
  }
  if (l == 0) {
#pragma unroll
    for (int o = 0; o < NLABEL; ++o) out[(size_t)b * NLABEL + o] = p[o] + bd[o];
  }
}

// ---------------- launch ----------------
extern "C" void kernel_launch(void* const* d_in, const int* in_sizes, int n_in,
                              void* d_out, int out_size, void* d_ws, size_t ws_size,
                              hipStream_t stream) {
  const int*   x          = (const int*)d_in[0];
  // d_in[1] = drop_rate (static 0, ignored)
  const float* emb_table  = (const float*)d_in[2];
  const float* kernel_w   = (const float*)d_in[3];
  const float* rec_kernel = (const float*)d_in[4];
  const float* bias_i     = (const float*)d_in[5];
  const float* bias_r     = (const float*)d_in[6];
  const float* Wd         = (const float*)d_in[7];
  const float* bd         = (const float*)d_in[8];
  float* out = (float*)d_out;

  char* ws = (char*)d_ws;
  size_t off = 0;
  auto alloc = [&](size_t bytes) {
    char* p = ws + off;
    off += (bytes + 255) & ~(size_t)255;
    return p;
  };
  float*    hf   = (float*)alloc((size_t)NB * H_DIM * 4);
  uint16_t* hb0  = (uint16_t*)alloc((size_t)NB * H_DIM * 2);
  uint16_t* hb1  = (uint16_t*)alloc((size_t)NB * H_DIM * 2);
  uint16_t* recT = (uint16_t*)alloc((size_t)G3 * H_DIM * 2);
  uint16_t* kerT = (uint16_t*)alloc((size_t)G3 * 64 * 2);
  uint16_t* embt = (uint16_t*)alloc((size_t)TSTEPS * NB * 64 * 2);
  uint32_t* cnt  = (uint32_t*)alloc(256);
  if (off > ws_size) return;  // insufficient workspace -> fail loudly

  hipMemsetAsync(hb0, 0, (size_t)NB * H_DIM * 2, stream);
  hipMemsetAsync(cnt, 0, 256, stream);

  prep_recT<<<dim3(G3 / 64, H_DIM / 64), 256, 0, stream>>>(rec_kernel, recT);
  prep_kerT<<<G3 / 4, 256, 0, stream>>>(kernel_w, kerT);
  prep_embt<<<TSTEPS * NB * 32 / 256, 256, 0, stream>>>(x, emb_table, embt);

  const uint16_t* embt_c = embt;
  const uint16_t* recT_c = recT;
  const uint16_t* kerT_c = kerT;
  void* kargs[] = {(void*)&hb0, (void*)&hb1, (void*)&hf,
                   (void*)&recT_c, (void*)&kerT_c, (void*)&embt_c,
                   (void*)&bias_i, (void*)&bias_r, (void*)&cnt};
  hipLaunchCooperativeKernel(reinterpret_cast<void*>(gru_persistent),
                             dim3(256), dim3(512), kargs, 0, stream);

  logits_kernel<<<NB, 64, 0, stream>>>(hf, Wd, bd, out);
}

// Round 7
// 3504.108 us; speedup vs baseline: 1.7764x; 1.7764x over previous
//
#include <hip/hip_runtime.h>
#include <stdint.h>

#define H_DIM   1024
#define G3      3072
#define EMB     50
#define TSTEPS  100
#define NB      4096
#define NLABEL  15

typedef __bf16 bf16x8 __attribute__((ext_vector_type(8)));
typedef float  f32x4  __attribute__((ext_vector_type(4)));

__device__ inline uint16_t f2bf(float f) {
  uint32_t u = __builtin_bit_cast(uint32_t, f);
  u += 0x7FFFu + ((u >> 16) & 1u);   // round-to-nearest-even
  return (uint16_t)(u >> 16);
}

__device__ inline void gld16(const void* g, void* l) {
  __builtin_amdgcn_global_load_lds(
      (const __attribute__((address_space(1))) uint32_t*)g,
      (__attribute__((address_space(3))) uint32_t*)l, 16, 0, 0);
}

#define BARF() do { __builtin_amdgcn_s_barrier(); \
                    asm volatile("" ::: "memory"); } while (0)

// ---------------- prep kernels (buffers stay LINEAR) ----------------

__global__ __launch_bounds__(256) void prep_recT(const float* __restrict__ rec,
                                                 uint16_t* __restrict__ recT) {
  __shared__ uint16_t st[64][72];
  const int n0 = blockIdx.x * 64;
  const int k0 = blockIdx.y * 64;
  const int tid = threadIdx.x;
#pragma unroll
  for (int i = 0; i < 16; ++i) {
    int idx = tid + i * 256;
    int r = idx >> 6;
    int c = idx & 63;
    st[c][r] = f2bf(rec[(size_t)(k0 + r) * G3 + n0 + c]);
  }
  __syncthreads();
#pragma unroll
  for (int i = 0; i < 16; ++i) {
    int idx = tid + i * 256;
    int r = idx >> 6;
    int c = idx & 63;
    recT[(size_t)(n0 + r) * H_DIM + k0 + c] = st[r][c];
  }
}

__global__ __launch_bounds__(256) void prep_kerT(const float* __restrict__ ker,
                                                 uint16_t* __restrict__ kerT) {
  int n = blockIdx.x * 4 + (threadIdx.x >> 6);
  int k = threadIdx.x & 63;
  float v = (k < EMB) ? ker[(size_t)k * G3 + n] : 0.f;
  kerT[(size_t)n * 64 + k] = f2bf(v);
}

__global__ __launch_bounds__(256) void prep_embt(const int* __restrict__ x,
                                                 const float* __restrict__ tab,
                                                 uint16_t* __restrict__ embt) {
  int idx = blockIdx.x * 256 + threadIdx.x;
  int g = idx >> 5;
  int p = idx & 31;
  int t = g >> 12;
  int b = g & 4095;
  int row = x[b * TSTEPS + t];
  float2 v;
  if (p < 25) v = *reinterpret_cast<const float2*>(tab + (size_t)row * EMB + 2 * p);
  else { v.x = 0.f; v.y = 0.f; }
  uint32_t packed = (uint32_t)f2bf(v.x) | ((uint32_t)f2bf(v.y) << 16);
  *reinterpret_cast<uint32_t*>(embt + (size_t)g * 64 + 2 * p) = packed;
}

// ---------------- fused GRU step ----------------
// grid 512 (2 blocks/CU for cross-block pipe overlap), block 256 (4 waves,
// 2x2). Tile: 128 rows x 64 cols, 3 gates. LDS exactly 80 KB -> 2 wg/CU.
// r5's counted-vmcnt phased pipeline (per-tile items 10; steady waits 8/4/8).
// XOR-swizzled LDS. XCD remap: each XCD = 8 rowblks x 8 colblks.
__global__ __launch_bounds__(256, 2) void gru_step_kernel(
    const uint16_t* __restrict__ hb_prev,   // [4096][1024] bf16
    float* __restrict__ hf,                 // [4096][1024] f32 (in-place)
    uint16_t* __restrict__ hb_next,         // [4096][1024] bf16
    const uint16_t* __restrict__ recT,      // [3072][1024] bf16
    const uint16_t* __restrict__ kerT,      // [3072][64]   bf16
    const uint16_t* __restrict__ embt,      // [4096][64]   bf16 (this step)
    const float* __restrict__ bias_i,       // [3072]
    const float* __restrict__ bias_r) {     // [3072]
  __shared__ __align__(16) uint16_t sA2[2][128 * 64];     // 32 KB
  __shared__ __align__(16) uint16_t sP[2][3][64 * 64];    // 48 KB

  const int tid  = threadIdx.x;
  const int lane = tid & 63;
  const int wid  = tid >> 6;     // 0..3
  const int wm   = wid >> 1;     // wave row 0..1 (64 rows each)
  const int wn   = wid & 1;      // wave col 0..1 (32 cols each)
  const int bid  = blockIdx.x;
  // XCD remap: xk = bid%8 -> XCD; each XCD: 8 rowblks x 8 colblks
  const int xk = bid & 7, slot = bid >> 3;          // slot 0..63
  const int rowblk = (xk >> 1) * 8 + (slot >> 3);   // 0..31
  const int colblk = (xk & 1) * 8 + (slot & 7);     // 0..15
  const int r0 = rowblk * 128;
  const int j0 = colblk * 64;

  // staged chunk covers row with row&7 == lane>>3 -> swizzled source col:
  const int swz8 = 8 * ((lane & 7) ^ (lane >> 3));

  bf16x8 af[4][2];               // A-frags (single-buffered)
  bf16x8 bf0[2][2], bf1[2][2];   // B-frag double buffer
  f32x4 accZ[4][2], accR[4][2], accH[4][2], accX[4][2];
#pragma unroll
  for (int m = 0; m < 4; ++m)
#pragma unroll
    for (int n = 0; n < 2; ++n) {
      accZ[m][n] = (f32x4){0.f, 0.f, 0.f, 0.f};
      accR[m][n] = (f32x4){0.f, 0.f, 0.f, 0.f};
      accH[m][n] = (f32x4){0.f, 0.f, 0.f, 0.f};
      accX[m][n] = (f32x4){0.f, 0.f, 0.f, 0.f};
    }

  // stage A-tile for tile t (4 gld16/thread, 16 KB)
  auto stageA = [&](int t) {
    const int abuf = t & 1;
#pragma unroll
    for (int i = 0; i < 4; ++i) {
      int chunk = wid * 4 + i;                // 0..15
      int row = chunk * 8 + (lane >> 3);
      const uint16_t* src = (t < 16)
          ? hb_prev + (size_t)(r0 + row) * H_DIM + t * 64 + swz8
          : embt + (size_t)(r0 + row) * 64 + swz8;
      gld16(src, &sA2[abuf][(chunk * 64 + lane) * 8]);
    }
  };
  // stage B-panel g of tile t (2 gld16/thread, 8 KB)
  auto stageP = [&](int t, int g) {
    const int pbuf = t & 1;
#pragma unroll
    for (int i = 0; i < 2; ++i) {
      int c = wid * 2 + i;                    // 0..7
      int n = c * 8 + (lane >> 3);            // 0..63
      const uint16_t* src = (t < 16)
          ? recT + ((size_t)g * H_DIM + j0 + n) * H_DIM + t * 64 + swz8
          : kerT + ((size_t)g * H_DIM + j0 + n) * 64 + swz8;
      gld16(src, &sP[pbuf][g][(c * 64 + lane) * 8]);
    }
  };
  // read A fragments for tile t into af[][] (8 ds_read_b128)
  auto readA = [&](int t) {
    const int abuf = t & 1;
#pragma unroll
    for (int ks = 0; ks < 2; ++ks) {
      const int colswz = (ks * 32 + (lane >> 4) * 8) ^ ((lane & 7) << 3);
#pragma unroll
      for (int mf = 0; mf < 4; ++mf)
        af[mf][ks] = *reinterpret_cast<const bf16x8*>(
            &sA2[abuf][(wm * 64 + mf * 16 + (lane & 15)) * 64 + colswz]);
    }
  };
  // read B fragments of panel g, tile t (4 ds_read_b128)
  auto readB = [&](int t, int g, bf16x8 (&bf)[2][2]) {
    const int pbuf = t & 1;
#pragma unroll
    for (int ks = 0; ks < 2; ++ks) {
      const int colswz = (ks * 32 + (lane >> 4) * 8) ^ ((lane & 7) << 3);
#pragma unroll
      for (int nf = 0; nf < 2; ++nf) {
        int nn = wn * 32 + nf * 16 + (lane & 15);   // 0..63
        bf[nf][ks] = *reinterpret_cast<const bf16x8*>(&sP[pbuf][g][nn * 64 + colswz]);
      }
    }
  };
  // 16 MFMA: af x bf -> acc
  auto MF = [&](bf16x8 (&bf)[2][2], f32x4 (&acc)[4][2]) {
    __builtin_amdgcn_s_setprio(1);
#pragma unroll
    for (int ks = 0; ks < 2; ++ks)
#pragma unroll
      for (int nf = 0; nf < 2; ++nf)
#pragma unroll
        for (int mf = 0; mf < 4; ++mf)
          acc[mf][nf] = __builtin_amdgcn_mfma_f32_16x16x32_bf16(
              af[mf][ks], bf[nf][ks], acc[mf][nf], 0, 0, 0);
    __builtin_amdgcn_s_setprio(0);
  };

#define PH(DSRD, MFBUF, MFACC, STG, WN) do { \
    DSRD; MF(MFBUF, MFACC); STG; \
    asm volatile("s_waitcnt vmcnt(" #WN ")" ::: "memory"); \
    BARF(); \
  } while (0)
#define PHH(MFBUF, MFACC, DSRD, STG, WN) do { \
    MF(MFBUF, MFACC); DSRD; STG; \
    asm volatile("s_waitcnt vmcnt(" #WN ")" ::: "memory"); \
    BARF(); \
  } while (0)
// steady tile (per-tile FIFO: P1(t+1)2, P2(t+1)2, A(t+2)4, P0(t+2)2)
#define TILE_STEADY(t, BFA, BFB) do { \
    PH(readB(t, 1, BFB), BFA, accZ, stageP((t) + 1, 1), 8); \
    PH(readB(t, 2, BFA), BFB, accR, stageP((t) + 1, 2), 4); \
    PHH(BFA, accH, (readA((t) + 1), readB((t) + 1, 0, BFB)), \
        (stageA((t) + 2), stageP((t) + 2, 0)), 8); \
  } while (0)

  // -------- prologue: tile 0 fully + A(1),P0(1); drain; pre-read frags ------
  stageA(0); stageP(0, 0); stageP(0, 1); stageP(0, 2);
  stageA(1); stageP(1, 0);
  asm volatile("s_waitcnt vmcnt(0)" ::: "memory");
  BARF();
  readA(0); readB(0, 0, bf0);

  // -------- main loop: tiles 0..13 (2-tile unroll for bf parity), then 14 ---
  for (int tt = 0; tt < 14; tt += 2) {
    TILE_STEADY(tt, bf0, bf1);
    TILE_STEADY(tt + 1, bf1, bf0);
  }
  TILE_STEADY(14, bf0, bf1);
  // tile 15 (odd): tail-exact counts
  PH(readB(15, 1, bf0), bf1, accZ, stageP(16, 1), 8);
  PH(readB(15, 2, bf1), bf0, accR, stageP(16, 2), 4);
  PHH(bf1, accH, (readA(16), readB(16, 0, bf0)), (void)0, 2);
  // tile 16 (even, input projection; h-gate -> accX)
  PH(readB(16, 1, bf1), bf0, accZ, (void)0, 0);
  PH(readB(16, 2, bf0), bf1, accR, (void)0, 0);
  MF(bf0, accX);

#undef PH
#undef PHH
#undef TILE_STEADY

  // -------- epilogue: gates in fp32, write h (f32 master + bf16) --------
#pragma unroll
  for (int nf = 0; nf < 2; ++nf) {
    int col = j0 + wn * 32 + nf * 16 + (lane & 15);
    float b_z = bias_i[col] + bias_r[col];
    float b_r = bias_i[H_DIM + col] + bias_r[H_DIM + col];
    float bih = bias_i[2 * H_DIM + col];
    float brh = bias_r[2 * H_DIM + col];
#pragma unroll
    for (int mf = 0; mf < 4; ++mf) {
#pragma unroll
      for (int q = 0; q < 4; ++q) {
        int row = r0 + wm * 64 + mf * 16 + (lane >> 4) * 4 + q;
        float z  = 1.f / (1.f + __expf(-(accZ[mf][nf][q] + b_z)));
        float rr = 1.f / (1.f + __expf(-(accR[mf][nf][q] + b_r)));
        float pre = accX[mf][nf][q] + bih + rr * (accH[mf][nf][q] + brh);
        float hc  = 2.f / (1.f + __expf(-2.f * pre)) - 1.f;   // tanh
        size_t idx = (size_t)row * H_DIM + col;
        float hold = hf[idx];
        float hnew = z * hold + (1.f - z) * hc;
        hf[idx] = hnew;
        hb_next[idx] = f2bf(hnew);
      }
    }
  }
}

// ---------------- final logits ----------------
__global__ __launch_bounds__(64) void logits_kernel(const float* __restrict__ hf,
                                                    const float* __restrict__ Wd,
                                                    const float* __restrict__ bd,
                                                    float* __restrict__ out) {
  int b = blockIdx.x;
  int l = threadIdx.x;
  float p[NLABEL];
#pragma unroll
  for (int o = 0; o < NLABEL; ++o) p[o] = 0.f;
  for (int kb = 0; kb < 16; ++kb) {
    int k = kb * 64 + l;
    float hv = hf[(size_t)b * H_DIM + k];
#pragma unroll
    for (int o = 0; o < NLABEL; ++o) p[o] += hv * Wd[k * NLABEL + o];
  }
#pragma unroll
  for (int o = 0; o < NLABEL; ++o) {
#pragma unroll
    for (int s = 32; s; s >>= 1) p[o] += __shfl_xor(p[o], s);
  }
  if (l == 0) {
#pragma unroll
    for (int o = 0; o < NLABEL; ++o) out[(size_t)b * NLABEL + o] = p[o] + bd[o];
  }
}

// ---------------- launch ----------------
extern "C" void kernel_launch(void* const* d_in, const int* in_sizes, int n_in,
                              void* d_out, int out_size, void* d_ws, size_t ws_size,
                              hipStream_t stream) {
  const int*   x          = (const int*)d_in[0];
  // d_in[1] = drop_rate (static 0, ignored)
  const float* emb_table  = (const float*)d_in[2];
  const float* kernel_w   = (const float*)d_in[3];
  const float* rec_kernel = (const float*)d_in[4];
  const float* bias_i     = (const float*)d_in[5];
  const float* bias_r     = (const float*)d_in[6];
  const float* Wd         = (const float*)d_in[7];
  const float* bd         = (const float*)d_in[8];
  float* out = (float*)d_out;

  char* ws = (char*)d_ws;
  size_t off = 0;
  auto alloc = [&](size_t bytes) {
    char* p = ws + off;
    off += (bytes + 255) & ~(size_t)255;
    return p;
  };
  float*    hf   = (float*)alloc((size_t)NB * H_DIM * 4);
  uint16_t* hb0  = (uint16_t*)alloc((size_t)NB * H_DIM * 2);
  uint16_t* hb1  = (uint16_t*)alloc((size_t)NB * H_DIM * 2);
  uint16_t* recT = (uint16_t*)alloc((size_t)G3 * H_DIM * 2);
  uint16_t* kerT = (uint16_t*)alloc((size_t)G3 * 64 * 2);
  uint16_t* embt = (uint16_t*)alloc((size_t)TSTEPS * NB * 64 * 2);
  if (off > ws_size) return;  // insufficient workspace -> fail loudly

  hipMemsetAsync(hf, 0, (size_t)NB * H_DIM * 4, stream);
  hipMemsetAsync(hb0, 0, (size_t)NB * H_DIM * 2, stream);

  prep_recT<<<dim3(G3 / 64, H_DIM / 64), 256, 0, stream>>>(rec_kernel, recT);
  prep_kerT<<<G3 / 4, 256, 0, stream>>>(kernel_w, kerT);
  prep_embt<<<TSTEPS * NB * 32 / 256, 256, 0, stream>>>(x, emb_table, embt);

  uint16_t* hb[2] = {hb0, hb1};
  for (int t = 0; t < TSTEPS; ++t) {
    gru_step_kernel<<<512, 256, 0, stream>>>(
        hb[t & 1], hf, hb[(t + 1) & 1], recT, kerT,
        embt + (size_t)t * NB * 64, bias_i, bias_r);
  }
  logits_kernel<<<NB, 64, 0, stream>>>(hf, Wd, bd, out);
}